// Round 1
// baseline (979.644 us; speedup 1.0000x reference)
//
#include <hip/hip_runtime.h>
#include <stdint.h>

#define N_SITES 1024
#define BS 2048
#define BLOCK 256
#define SPT 4      // samples per thread -> 2 blocks cover the batch per row
#define CHUNK 64   // columns staged in LDS per chunk (64*32 floats = 8 KB)

// Pack spin-selection bits, transposed: bitsT[w*BS + b], bit (j&31) of word j>>5
// sel = 0 if spin==1 (phys index 0), 1 if spin==0.
__global__ void pack_bits_kernel(const float* __restrict__ data,
                                 uint32_t* __restrict__ bitsT) {
  int idx = blockIdx.x * blockDim.x + threadIdx.x;  // 0..65535
  int w = idx >> 11;   // word 0..31
  int b = idx & 2047;  // sample
  const float* p = data + ((size_t)b * N_SITES + (size_t)w * 32) * 2;
  uint32_t word = 0;
#pragma unroll
  for (int t = 0; t < 32; ++t) {
    float spin = p[2 * t];
    word |= (spin < 0.5f ? 1u : 0u) << t;
  }
  bitsT[(size_t)w * BS + b] = word;
}

__global__ void zero_out_kernel(float* __restrict__ out) {
  int i = blockIdx.x * blockDim.x + threadIdx.x;
  if (i < BS) out[i] = 0.0f;
}

// One block handles (row n, half of batch). Chain of 4x4 matvecs over columns.
__global__ __launch_bounds__(BLOCK) void amps_rows_kernel(
    const float* __restrict__ tensors, const uint32_t* __restrict__ bitsT,
    float* __restrict__ out) {
  __shared__ float lds[CHUNK * 32];

  const int bid = (int)blockIdx.x;
  const int n = (N_SITES - 1) - (bid >> 1);  // longest rows first
  const int half = bid & 1;
  const int tid = (int)threadIdx.x;
  const int b0 = half * (BLOCK * SPT) + tid;  // sample s lives at b0 + s*BLOCK

  // L init = e0: makes column j=0 produce T[n,0,0,:,sel] via the uniform body.
  float L[SPT][4];
#pragma unroll
  for (int s = 0; s < SPT; ++s) {
    L[s][0] = 1.f; L[s][1] = 0.f; L[s][2] = 0.f; L[s][3] = 0.f;
  }

  const float* rowp = tensors + (size_t)n * N_SITES * 32;

  for (int c0 = 0; c0 < n; c0 += CHUNK) {
    const int cols = min(CHUNK, n - c0);
    // cooperative coalesced stage: cols*32 floats (both phys matrices)
    const int nf4 = cols * 8;
    const float4* g4 = (const float4*)(rowp + (size_t)c0 * 32);
    float4* l4 = (float4*)lds;
    for (int i = tid; i < nf4; i += BLOCK) l4[i] = g4[i];
    __syncthreads();

    for (int sub = 0; sub < cols; sub += 32) {
      const int w = (c0 + sub) >> 5;
      uint32_t bw[SPT];
#pragma unroll
      for (int s = 0; s < SPT; ++s)
        bw[s] = bitsT[(size_t)w * BS + (size_t)(b0 + s * BLOCK)];
      const int jend = min(32, cols - sub);
      for (int jj = 0; jj < jend; ++jj) {
        // broadcast read of both 4x4 matrices for this column: 8x ds_read_b128
        const float4* mp4 = (const float4*)(lds + (sub + jj) * 32);
        float m[32];
#pragma unroll
        for (int q = 0; q < 8; ++q) {
          float4 v = mp4[q];
          m[4 * q + 0] = v.x; m[4 * q + 1] = v.y;
          m[4 * q + 2] = v.z; m[4 * q + 3] = v.w;
        }
#pragma unroll
        for (int s = 0; s < SPT; ++s) {
          const bool sel = (bw[s] >> jj) & 1u;
          float acc0 = 0.f, acc1 = 0.f, acc2 = 0.f, acc3 = 0.f;
#pragma unroll
          for (int a = 0; a < 4; ++a) {
            const float lv = L[s][a];
            // entry (l=a, r=k, i): offset a*8 + k*2 + i
            const float m0 = sel ? m[a * 8 + 1] : m[a * 8 + 0];
            const float m1 = sel ? m[a * 8 + 3] : m[a * 8 + 2];
            const float m2 = sel ? m[a * 8 + 5] : m[a * 8 + 4];
            const float m3 = sel ? m[a * 8 + 7] : m[a * 8 + 6];
            acc0 = fmaf(lv, m0, acc0);
            acc1 = fmaf(lv, m1, acc1);
            acc2 = fmaf(lv, m2, acc2);
            acc3 = fmaf(lv, m3, acc3);
          }
          L[s][0] = acc0; L[s][1] = acc1; L[s][2] = acc2; L[s][3] = acc3;
        }
      }
    }
    __syncthreads();
  }

  // Epilogue: logits_i = sum_a L[a] * T[n,n,a,0,i]; contribution = logsoftmax[sel_n]
  const float* dgp = tensors + ((size_t)n * N_SITES + n) * 32;
  float dg0[4], dg1[4];
#pragma unroll
  for (int a = 0; a < 4; ++a) {
    dg0[a] = dgp[a * 8 + 0];
    dg1[a] = dgp[a * 8 + 1];
  }
  const int wN = n >> 5;
#pragma unroll
  for (int s = 0; s < SPT; ++s) {
    const int b = b0 + s * BLOCK;
    const uint32_t word = bitsT[(size_t)wN * BS + b];
    const int sel = (word >> (n & 31)) & 1u;
    float l0 = 0.f, l1 = 0.f;
#pragma unroll
    for (int a = 0; a < 4; ++a) {
      l0 = fmaf(L[s][a], dg0[a], l0);
      l1 = fmaf(L[s][a], dg1[a], l1);
    }
    const float mx = fmaxf(l0, l1);
    const float lse = mx + logf(expf(l0 - mx) + expf(l1 - mx));
    const float c = (sel ? l1 : l0) - lse;
    atomicAdd(&out[b], c);
  }
}

extern "C" void kernel_launch(void* const* d_in, const int* in_sizes, int n_in,
                              void* d_out, int out_size, void* d_ws, size_t ws_size,
                              hipStream_t stream) {
  const float* data = (const float*)d_in[0];     // (BS, N, 2) fp32
  const float* tensors = (const float*)d_in[1];  // (N, N, 4, 4, 2) fp32
  float* out = (float*)d_out;                    // (BS,) fp32
  uint32_t* bitsT = (uint32_t*)d_ws;             // needs 32*2048*4 = 256 KB

  pack_bits_kernel<<<(32 * BS) / BLOCK, BLOCK, 0, stream>>>(data, bitsT);
  zero_out_kernel<<<(BS + BLOCK - 1) / BLOCK, BLOCK, 0, stream>>>(out);
  amps_rows_kernel<<<N_SITES * 2, BLOCK, 0, stream>>>(tensors, bitsT, out);
}

// Round 2
// 347.252 us; speedup vs baseline: 2.8211x; 2.8211x over previous
//
#include <hip/hip_runtime.h>
#include <stdint.h>

#define N_SITES 1024
#define BS 2048
#define BLOCK 512
#define SPT 4            // 512 threads * 4 samples = 2048 = BS
#define SEGCHUNK 16      // segments per chunk = 64 columns
#define SEG_FLOATS 320   // 16 sels * 20 floats (16 data + 4 pad -> 80B stride)

// Pack spin-selection bits, transposed: bitsT[w*BS + b], bit (j&31) of word j>>5.
// sel = 0 if spin==1 (phys 0), 1 if spin==0 (phys 1).
__global__ void pack_bits_kernel(const float* __restrict__ data,
                                 uint32_t* __restrict__ bitsT) {
  int idx = blockIdx.x * blockDim.x + threadIdx.x;  // 0..65535
  int w = idx >> 11;   // word 0..31
  int b = idx & 2047;  // sample
  const float* p = data + ((size_t)b * N_SITES + (size_t)w * 32) * 2;
  uint32_t word = 0;
#pragma unroll
  for (int t = 0; t < 32; ++t) {
    float spin = p[2 * t];
    word |= (spin < 0.5f ? 1u : 0u) << t;
  }
  bitsT[(size_t)w * BS + b] = word;
}

__global__ void zero_out_kernel(float* __restrict__ out) {
  int i = blockIdx.x * blockDim.x + threadIdx.x;
  if (i < BS) out[i] = 0.0f;
}

// One block per row n (longest first). Chain of 4x4 matvecs over columns j<n,
// processed 4 columns at a time via in-LDS precomputed 16-way segment products.
__global__ __launch_bounds__(BLOCK) void amps_fused_kernel(
    const float* __restrict__ tensors, const uint32_t* __restrict__ bitsT,
    float* __restrict__ out) {
  __shared__ float colsL[64 * 32];                 // 8 KB: 64 raw columns
  __shared__ float segL[SEGCHUNK * SEG_FLOATS];    // 20 KB: 16 segs x 16 sels x 20f
  __shared__ float tailL[3 * 32];                  // tail cols, [c][sel][a*4+k]

  const int bid = (int)blockIdx.x;
  const int n = (N_SITES - 1) - bid;  // longest rows first
  const int tid = (int)threadIdx.x;
  const int T = n >> 2, r = n & 3;
  const size_t rowbase = (size_t)n * (N_SITES * 32);

  float L[SPT][4];
#pragma unroll
  for (int s = 0; s < SPT; ++s) {
    L[s][0] = 1.f; L[s][1] = 0.f; L[s][2] = 0.f; L[s][3] = 0.f;
  }

  // Stage tail columns transposed: tailL[c*32 + sel*16 + a*4 + k]
  if (r > 0 && tid < r * 32) {
    int c = tid >> 5, e = tid & 31;
    int a = e >> 3, k = (e >> 1) & 3, i = e & 1;
    tailL[c * 32 + i * 16 + a * 4 + k] =
        tensors[rowbase + (size_t)(4 * T + c) * 32 + a * 8 + k * 2 + i];
  }
  if (T == 0 && r > 0) __syncthreads();

  const int sel16 = tid & 15, slp = tid >> 4;  // product-phase role (slp<16 active)

  for (int cs = 0; cs < T; cs += SEGCHUNK) {
    const int ns = min(SEGCHUNK, T - cs);
    __syncthreads();  // previous chunk fully consumed before overwrite
    // stage 64 raw columns [4*cs, 4*cs+64): 512 float4s, one per thread
    {
      const float4* g4 = (const float4*)(tensors + rowbase + (size_t)cs * 4 * 32);
      ((float4*)colsL)[tid] = g4[tid];
    }
    __syncthreads();
    // product phase: thread (slp, sel16) builds M(b0)*M(b1)*M(b2)*M(b3)
    if (slp < ns) {
      const float* cp = colsL + (slp * 4) * 32;
      float R[16];
      {
        int b = sel16 & 1;
#pragma unroll
        for (int a = 0; a < 4; ++a)
#pragma unroll
          for (int k = 0; k < 4; ++k) R[a * 4 + k] = cp[a * 8 + k * 2 + b];
      }
#pragma unroll
      for (int c = 1; c < 4; ++c) {
        int b = (sel16 >> c) & 1;
        const float* mc = cp + c * 32;
        float m[16];
#pragma unroll
        for (int x = 0; x < 4; ++x)
#pragma unroll
          for (int k = 0; k < 4; ++k) m[x * 4 + k] = mc[x * 8 + k * 2 + b];
        float Rn[16];
#pragma unroll
        for (int a = 0; a < 4; ++a)
#pragma unroll
          for (int k = 0; k < 4; ++k) {
            float acc = R[a * 4] * m[k];
            acc = fmaf(R[a * 4 + 1], m[4 + k], acc);
            acc = fmaf(R[a * 4 + 2], m[8 + k], acc);
            acc = fmaf(R[a * 4 + 3], m[12 + k], acc);
            Rn[a * 4 + k] = acc;
          }
#pragma unroll
        for (int i2 = 0; i2 < 16; ++i2) R[i2] = Rn[i2];
      }
      float* dst = segL + slp * SEG_FLOATS + sel16 * 20;
#pragma unroll
      for (int i2 = 0; i2 < 16; ++i2) dst[i2] = R[i2];
    }
    __syncthreads();
    // processing phase: all 512 threads, SPT samples each
    uint32_t wd[SPT];
    for (int s = 0; s < ns; ++s) {
      const int g = cs + s;
      if ((s & 7) == 0) {  // cs is a multiple of 16, so (g&7)==(s&7)
        const size_t wb = (size_t)(g >> 3) * BS + tid;
#pragma unroll
        for (int sp = 0; sp < SPT; ++sp) wd[sp] = bitsT[wb + sp * BLOCK];
      }
      const uint32_t sh = (uint32_t)((g & 7) * 4);
      const float* sbase = segL + s * SEG_FLOATS;
#pragma unroll
      for (int sp = 0; sp < SPT; ++sp) {
        const int sel = (int)((wd[sp] >> sh) & 15u);
        const float4* mp = (const float4*)(sbase + sel * 20);
        float4 m0 = mp[0], m1 = mp[1], m2 = mp[2], m3 = mp[3];
        const float a0 = L[sp][0], a1 = L[sp][1], a2 = L[sp][2], a3 = L[sp][3];
        L[sp][0] = fmaf(a3, m3.x, fmaf(a2, m2.x, fmaf(a1, m1.x, a0 * m0.x)));
        L[sp][1] = fmaf(a3, m3.y, fmaf(a2, m2.y, fmaf(a1, m1.y, a0 * m0.y)));
        L[sp][2] = fmaf(a3, m3.z, fmaf(a2, m2.z, fmaf(a1, m1.z, a0 * m0.z)));
        L[sp][3] = fmaf(a3, m3.w, fmaf(a2, m2.w, fmaf(a1, m1.w, a0 * m0.w)));
      }
    }
  }

  // tail columns j = 4T .. n-1 via 1-bit indexed LDS read
  for (int c = 0; c < r; ++c) {
    const int j = 4 * T + c;
    const uint32_t sh = (uint32_t)(j & 31);
    const size_t wb = (size_t)(j >> 5) * BS + tid;
    const float* tbase = tailL + c * 32;
#pragma unroll
    for (int sp = 0; sp < SPT; ++sp) {
      const uint32_t bit = (bitsT[wb + sp * BLOCK] >> sh) & 1u;
      const float4* mp = (const float4*)(tbase + bit * 16);
      float4 m0 = mp[0], m1 = mp[1], m2 = mp[2], m3 = mp[3];
      const float a0 = L[sp][0], a1 = L[sp][1], a2 = L[sp][2], a3 = L[sp][3];
      L[sp][0] = fmaf(a3, m3.x, fmaf(a2, m2.x, fmaf(a1, m1.x, a0 * m0.x)));
      L[sp][1] = fmaf(a3, m3.y, fmaf(a2, m2.y, fmaf(a1, m1.y, a0 * m0.y)));
      L[sp][2] = fmaf(a3, m3.z, fmaf(a2, m2.z, fmaf(a1, m1.z, a0 * m0.z)));
      L[sp][3] = fmaf(a3, m3.w, fmaf(a2, m2.w, fmaf(a1, m1.w, a0 * m0.w)));
    }
  }

  // epilogue: logits from diagonal tensor, 2-way log-softmax, pick observed
  const float* dgp = tensors + rowbase + (size_t)n * 32;
  float dg0[4], dg1[4];
#pragma unroll
  for (int a = 0; a < 4; ++a) {
    dg0[a] = dgp[a * 8 + 0];
    dg1[a] = dgp[a * 8 + 1];
  }
  const size_t wb = (size_t)(n >> 5) * BS + tid;
  const uint32_t shn = (uint32_t)(n & 31);
#pragma unroll
  for (int sp = 0; sp < SPT; ++sp) {
    const int b = tid + sp * BLOCK;
    const uint32_t sel = (bitsT[wb + sp * BLOCK] >> shn) & 1u;
    float l0 = 0.f, l1 = 0.f;
#pragma unroll
    for (int a = 0; a < 4; ++a) {
      l0 = fmaf(L[sp][a], dg0[a], l0);
      l1 = fmaf(L[sp][a], dg1[a], l1);
    }
    const float mx = fmaxf(l0, l1);
    const float lse = mx + logf(expf(l0 - mx) + expf(l1 - mx));
    atomicAdd(&out[b], (sel ? l1 : l0) - lse);
  }
}

extern "C" void kernel_launch(void* const* d_in, const int* in_sizes, int n_in,
                              void* d_out, int out_size, void* d_ws, size_t ws_size,
                              hipStream_t stream) {
  const float* data = (const float*)d_in[0];     // (BS, N, 2) fp32
  const float* tensors = (const float*)d_in[1];  // (N, N, 4, 4, 2) fp32
  float* out = (float*)d_out;                    // (BS,) fp32
  uint32_t* bitsT = (uint32_t*)d_ws;             // 32*2048*4 = 256 KB

  pack_bits_kernel<<<(32 * BS) / 256, 256, 0, stream>>>(data, bitsT);
  zero_out_kernel<<<(BS + 255) / 256, 256, 0, stream>>>(out);
  amps_fused_kernel<<<N_SITES, BLOCK, 0, stream>>>(tensors, bitsT, out);
}